// Round 3
// baseline (105.552 us; speedup 1.0000x reference)
//
#include <hip/hip_runtime.h>
#include <cfloat>

#define TPB 256
#define MS_DEFAULT 128

// ---------------------------------------------------------------------------
// Fused kernel.
// grid = PB * MS. Block (pb, c) computes partial two-smallest squared
// distances for its 256 trajectory points over obstacle chunk c, writes them
// to ws, then the LAST block of each pb group (atomic counter) merges the MS
// partials, computes all loss terms for those points, and the globally last
// merging block writes out[0]. Counters are zeroed by hipMemsetAsync before
// launch; no other state persists across calls.
// ---------------------------------------------------------------------------
__global__ __launch_bounds__(TPB) void traj_fused_kernel(
        const float2* __restrict__ traj,
        const float4* __restrict__ obs4,
        float2* __restrict__ part,      // [MS][N]
        int* __restrict__ cnt,          // [PB] chunk counters + cnt[PB] global
        float* __restrict__ bsum,       // [PB]
        float* __restrict__ out,
        int N, int M, int PB, int MS, int chunk) {
    const float HINV = 1.0f / 1024.0f;
    const int pb = blockIdx.x % PB;
    const int c  = blockIdx.x / PB;
    const int i  = pb * TPB + threadIdx.x;

    // ---- phase 1: partial two-smallest over chunk c ----
    if (i < N) {
        float2 tp = traj[i];
        const float px = tp.x * HINV;
        const float py = tp.y * HINV;
        float m1 = FLT_MAX, m2 = FLT_MAX;

        int k0 = c * chunk;
        int k1 = k0 + chunk; if (k1 > M) k1 = M;
        if (k0 < k1) {
            const int npairs = (k1 - k0) >> 1;
            const float4* o4 = obs4 + (k0 >> 1);
#pragma unroll 8
            for (int kp = 0; kp < npairs; ++kp) {
                float4 o = o4[kp];
                {
                    float dx = px - o.x, dy = py - o.y;
                    float d2 = __builtin_fmaf(dx, dx, dy * dy);
                    float n2 = __builtin_amdgcn_fmed3f(d2, m1, m2);
                    m1 = fminf(m1, d2);
                    m2 = n2;
                }
                {
                    float dx = px - o.z, dy = py - o.w;
                    float d2 = __builtin_fmaf(dx, dx, dy * dy);
                    float n2 = __builtin_amdgcn_fmed3f(d2, m1, m2);
                    m1 = fminf(m1, d2);
                    m2 = n2;
                }
            }
            if ((k1 - k0) & 1) {
                float2 o = ((const float2*)obs4)[k1 - 1];
                float dx = px - o.x, dy = py - o.y;
                float d2 = __builtin_fmaf(dx, dx, dy * dy);
                float n2 = __builtin_amdgcn_fmed3f(d2, m1, m2);
                m1 = fminf(m1, d2);
                m2 = n2;
            }
        }
        part[c * N + i] = make_float2(m1, m2);
    }

    // ---- signal chunk done; last block of this pb group merges ----
    __threadfence();                       // release partial writes
    __shared__ int sIsLast;
    if (threadIdx.x == 0) {
        int old = atomicAdd(&cnt[pb], 1);
        sIsLast = (old == MS - 1);
    }
    __syncthreads();
    if (!sIsLast) return;
    __threadfence();                       // acquire other chunks' writes

    // ---- phase 2: merge MS partials + loss terms for this pb's points ----
    float cval = 0.0f;
    if (i < N) {
        float a1 = FLT_MAX, a2 = FLT_MAX;
        for (int ch = 0; ch < MS; ++ch) {
            float2 b = part[ch * N + i];
            float lo = fminf(a1, b.x);
            float hi = fmaxf(a1, b.x);
            a2 = fminf(hi, fminf(a2, b.y));
            a1 = lo;
        }

        float d_obs = sqrtf(a1 + 1e-6f);
        float d_sec = sqrtf(a2 + 1e-6f);
        float d_vor = 0.5f * (d_sec - d_obs);
        float r = fmaxf(0.05f - d_obs, 0.0f);
        cval = 1000.0f * r * r;            // obstacle term (weight folded)
        if (d_obs <= 0.05f) {
            float q = d_obs - 0.05f;
            float rho = (0.1f / (0.1f + d_obs))
                      * (d_vor / (d_obs + d_vor + 1e-6f))
                      * (q * q) / (0.05f * 0.05f);
            cval += rho;                   // voronoi term
        }

        if (i <= N - 3) {                  // balance / curvature / steering
            float2 t0 = traj[i];
            float2 t1 = traj[i + 1];
            float2 t2 = traj[i + 2];
            float sx = t2.x - 2.0f * t1.x + t0.x;
            float sy = t2.y - 2.0f * t1.y + t0.y;
            cval += sx * sx + sy * sy;
            float d0x = t1.x - t0.x, d0y = t1.y - t0.y;
            float d1x = t2.x - t1.x, d1y = t2.y - t1.y;
            float th0 = atan2f(d0y, d0x);
            float th1 = atan2f(d1y, d1x);
            float dth = th1 - th0;
            const float PI_F = 3.14159265358979323846f;
            if (dth > PI_F) dth -= 2.0f * PI_F;
            else if (dth < -PI_F) dth += 2.0f * PI_F;
            float adth = fabsf(dth);
            float seg = sqrtf(d0x * d0x + d0y * d0y);
            float kappa = adth / (seg + 1e-6f);
            float rc = fmaxf(kappa - 0.04f, 0.0f);
            float rs = fmaxf(adth - 0.04f, 0.0f);
            cval += rc * rc + rs * rs;
        }
    }

    // block reduction
    float v = cval;
#pragma unroll
    for (int s = 32; s > 0; s >>= 1) v += __shfl_down(v, s, 64);
    __shared__ float wsum[TPB / 64];
    const int wave = threadIdx.x >> 6;
    const int lane = threadIdx.x & 63;
    if (lane == 0) wsum[wave] = v;
    __syncthreads();

    __shared__ int sIsFinal;
    if (threadIdx.x == 0) {
        float s = 0.0f;
#pragma unroll
        for (int w = 0; w < TPB / 64; ++w) s += wsum[w];
        bsum[pb] = s;
        __threadfence();                   // release bsum
        int old = atomicAdd(&cnt[PB], 1);
        sIsFinal = (old == PB - 1);
    }
    __syncthreads();
    if (!sIsFinal) return;

    if (threadIdx.x == 0) {
        __threadfence();                   // acquire other bsum writes
        float tot = 0.0f;
        for (int p = 0; p < PB; ++p) tot += bsum[p];
        out[0] = tot;
    }
}

extern "C" void kernel_launch(void* const* d_in, const int* in_sizes, int n_in,
                              void* d_out, int out_size, void* d_ws, size_t ws_size,
                              hipStream_t stream) {
    const float2* traj = (const float2*)d_in[0];
    const float4* obs4 = (const float4*)d_in[1];
    float* out = (float*)d_out;
    int N = in_sizes[0] / 2;
    int M = in_sizes[1] / 2;

    int PB = (N + TPB - 1) / TPB;          // 8 for N=2048

    int MS = MS_DEFAULT;
    while (MS > 1 &&
           (size_t)MS * (size_t)N * sizeof(float2) + (size_t)(PB + 1) * 4
               + (size_t)PB * 4 > ws_size) MS >>= 1;
    int chunk = (M + MS - 1) / MS;
    chunk += (chunk & 1);                  // even for float4 alignment

    size_t partBytes = (size_t)MS * (size_t)N * sizeof(float2);
    float2* part = (float2*)d_ws;
    int*    cnt  = (int*)((char*)d_ws + partBytes);
    float*  bsum = (float*)(cnt + PB + 1);

    // zero the counters (memset node; graph-capturable)
    hipMemsetAsync((void*)cnt, 0, (size_t)(PB + 1) * sizeof(int), stream);

    traj_fused_kernel<<<PB * MS, TPB, 0, stream>>>(
        traj, obs4, part, cnt, bsum, out, N, M, PB, MS, chunk);
}

// Round 4
// 21.447 us; speedup vs baseline: 4.9215x; 4.9215x over previous
//
#include <hip/hip_runtime.h>
#include <cfloat>

#define TPB 512
#define PPB 4                 // trajectory points per block
#define NWAVES (TPB / 64)

// ---------------------------------------------------------------------------
// Single fused kernel, no cross-block dependencies.
// Block b owns points [b*PPB, b*PPB+PPB). All 512 threads stride the full
// obstacle array (coalesced float4 = 2 obstacles), maintaining two-smallest
// squared distances for each of the 4 points in registers. In-wave shfl
// butterfly merges lanes; LDS merges the 8 waves; 4 threads compute the
// loss terms; one atomicAdd per block into out[0] (zeroed by memset node).
// ---------------------------------------------------------------------------
__global__ __launch_bounds__(TPB) void traj_fused(
        const float2* __restrict__ traj,
        const float4* __restrict__ obs4,
        float* __restrict__ out,
        int N, int M) {
    const float HINV = 1.0f / 1024.0f;
    const int t = threadIdx.x;
    const int pbase = blockIdx.x * PPB;

    float px[PPB], py[PPB], m1[PPB], m2[PPB];
#pragma unroll
    for (int p = 0; p < PPB; ++p) {
        int idx = pbase + p;
        float2 tp = traj[idx < N ? idx : N - 1];
        bool ok = idx < N;
        px[p] = ok ? tp.x * HINV : 1.0e9f;   // far away -> no contribution
        py[p] = ok ? tp.y * HINV : 1.0e9f;
        m1[p] = FLT_MAX;
        m2[p] = FLT_MAX;
    }

    // ---- pairwise pass: all threads stride the obstacle array ----
    const int npairs = M >> 1;
#pragma unroll 4
    for (int k = t; k < npairs; k += TPB) {
        float4 o = obs4[k];
#pragma unroll
        for (int p = 0; p < PPB; ++p) {
            {
                float dx = px[p] - o.x, dy = py[p] - o.y;
                float d2 = __builtin_fmaf(dx, dx, dy * dy);
                float n2 = __builtin_amdgcn_fmed3f(d2, m1[p], m2[p]);
                m1[p] = fminf(m1[p], d2);
                m2[p] = n2;
            }
            {
                float dx = px[p] - o.z, dy = py[p] - o.w;
                float d2 = __builtin_fmaf(dx, dx, dy * dy);
                float n2 = __builtin_amdgcn_fmed3f(d2, m1[p], m2[p]);
                m1[p] = fminf(m1[p], d2);
                m2[p] = n2;
            }
        }
    }
    if ((M & 1) && t == 0) {                 // odd tail (M even in practice)
        float2 o = ((const float2*)obs4)[M - 1];
#pragma unroll
        for (int p = 0; p < PPB; ++p) {
            float dx = px[p] - o.x, dy = py[p] - o.y;
            float d2 = __builtin_fmaf(dx, dx, dy * dy);
            float n2 = __builtin_amdgcn_fmed3f(d2, m1[p], m2[p]);
            m1[p] = fminf(m1[p], d2);
            m2[p] = n2;
        }
    }

    // ---- in-wave butterfly merge of (m1,m2) pairs ----
#pragma unroll
    for (int s = 1; s < 64; s <<= 1) {
#pragma unroll
        for (int p = 0; p < PPB; ++p) {
            float o1 = __shfl_xor(m1[p], s, 64);
            float o2 = __shfl_xor(m2[p], s, 64);
            float hi = fmaxf(m1[p], o1);
            m1[p] = fminf(m1[p], o1);
            m2[p] = fminf(fminf(m2[p], o2), hi);
        }
    }

    // ---- cross-wave merge via LDS (block-local, no fences) ----
    __shared__ float2 lm[NWAVES][PPB];
    __shared__ float contrib[PPB];
    const int wave = t >> 6;
    const int lane = t & 63;
    if (lane == 0) {
#pragma unroll
        for (int p = 0; p < PPB; ++p) lm[wave][p] = make_float2(m1[p], m2[p]);
    }
    __syncthreads();

    if (t < PPB) {
        const int p = t;
        const int i = pbase + p;
        float c = 0.0f;
        if (i < N) {
            float a1 = FLT_MAX, a2 = FLT_MAX;
#pragma unroll
            for (int w = 0; w < NWAVES; ++w) {
                float2 b = lm[w][p];
                float hi = fmaxf(a1, b.x);
                a1 = fminf(a1, b.x);
                a2 = fminf(fminf(a2, b.y), hi);
            }

            float d_obs = sqrtf(a1 + 1e-6f);
            float d_sec = sqrtf(a2 + 1e-6f);
            float d_vor = 0.5f * (d_sec - d_obs);
            float r = fmaxf(0.05f - d_obs, 0.0f);
            c = 1000.0f * r * r;             // obstacle term (weight folded)
            if (d_obs <= 0.05f) {
                float q = d_obs - 0.05f;
                float rho = (0.1f / (0.1f + d_obs))
                          * (d_vor / (d_obs + d_vor + 1e-6f))
                          * (q * q) / (0.05f * 0.05f);
                c += rho;                    // voronoi term
            }

            if (i <= N - 3) {                // balance / curvature / steering
                float2 t0 = traj[i];
                float2 t1 = traj[i + 1];
                float2 t2 = traj[i + 2];
                float sx = t2.x - 2.0f * t1.x + t0.x;
                float sy = t2.y - 2.0f * t1.y + t0.y;
                c += sx * sx + sy * sy;
                float d0x = t1.x - t0.x, d0y = t1.y - t0.y;
                float d1x = t2.x - t1.x, d1y = t2.y - t1.y;
                float th0 = atan2f(d0y, d0x);
                float th1 = atan2f(d1y, d1x);
                float dth = th1 - th0;
                const float PI_F = 3.14159265358979323846f;
                if (dth > PI_F) dth -= 2.0f * PI_F;
                else if (dth < -PI_F) dth += 2.0f * PI_F;
                float adth = fabsf(dth);
                float seg = sqrtf(d0x * d0x + d0y * d0y);
                float kappa = adth / (seg + 1e-6f);
                float rc = fmaxf(kappa - 0.04f, 0.0f);
                float rs = fmaxf(adth - 0.04f, 0.0f);
                c += rc * rc + rs * rs;
            }
        }
        contrib[p] = c;
    }
    __syncthreads();

    if (t == 0) {
        float s = 0.0f;
#pragma unroll
        for (int p = 0; p < PPB; ++p) s += contrib[p];
        atomicAdd(out, s);
    }
}

extern "C" void kernel_launch(void* const* d_in, const int* in_sizes, int n_in,
                              void* d_out, int out_size, void* d_ws, size_t ws_size,
                              hipStream_t stream) {
    const float2* traj = (const float2*)d_in[0];
    const float4* obs4 = (const float4*)d_in[1];
    float* out = (float*)d_out;
    int N = in_sizes[0] / 2;
    int M = in_sizes[1] / 2;

    hipMemsetAsync(d_out, 0, (size_t)out_size * sizeof(float), stream);

    int grid = (N + PPB - 1) / PPB;          // 512 blocks for N=2048
    traj_fused<<<grid, TPB, 0, stream>>>(traj, obs4, out, N, M);
}